// Round 1
// baseline (309.722 us; speedup 1.0000x reference)
//
#include <hip/hip_runtime.h>

#define NB   16
#define CINC 64
#define COUTC 64
#define NV   25
#define TLEN 512
#define KK   3
#define TKK  3

// ws layout:
//   [0, 512)   : normalized mask, 75 ints
//   [512, ...) : Wt[(v*3+k)*3+kt][c][o]  fp32, 921600 floats (3.69 MB)

__global__ void prep_mask_kernel(const int* __restrict__ mask_raw,
                                 int* __restrict__ mask_out) {
  __shared__ int fmt;
  if (threadIdx.x == 0) {
    // If the harness pushed bool as raw bytes, reading int32 over the
    // mostly-1 byte pattern yields values like 0x01010101 not in {0,1}.
    int ok = 1;
    for (int i = 0; i < 18; ++i) {   // 18 ints = 72 bytes, within 75-byte buf
      int m = mask_raw[i];
      if (m != 0 && m != 1) ok = 0;
    }
    fmt = ok;
  }
  __syncthreads();
  int i = threadIdx.x;
  if (i < NV * KK) {
    int m;
    if (fmt) m = mask_raw[i];
    else     m = (((const unsigned char*)mask_raw)[i] != 0) ? 1 : 0;
    mask_out[i] = m;
  }
}

// Wt[((v*3+k)*3+kt)][c][o] = W[v][o][c][k][kt]
__global__ void prep_wt_kernel(const float* __restrict__ W,
                               float* __restrict__ Wt) {
  int v   = blockIdx.x / 9;
  int kkt = blockIdx.x % 9;   // k*3+kt
  const float* Wv = W + (size_t)v * COUTC * CINC * 9;
  float* dst = Wt + (size_t)blockIdx.x * (CINC * COUTC);
  for (int i = threadIdx.x; i < CINC * COUTC; i += 256) {
    int c = i >> 6;
    int o = i & 63;
    dst[i] = Wv[(o * CINC + c) * 9 + kkt];
  }
}

__global__ __launch_bounds__(256, 4) void lcn_main(
    const float* __restrict__ x, const float* __restrict__ Wt,
    const float* __restrict__ b, const int* __restrict__ idx,
    const int* __restrict__ maskn, float* __restrict__ out) {
  __shared__ float xs[CINC][66];     // one neighbor slab, halo +-1
  __shared__ float wsh[CINC][COUTC]; // [c][o] for current (k,kt)

  const int tb  = blockIdx.x * 64;   // time base
  const int v   = blockIdx.y;
  const int n   = blockIdx.z;
  const int tid = threadIdx.x;
  const int t0  = tid & 63;          // time lane
  const int og  = tid >> 6;          // o-group: 16 outputs each

  float acc[16];
#pragma unroll
  for (int j = 0; j < 16; ++j) acc[j] = 0.f;

  for (int k = 0; k < KK; ++k) {
    const int vk = idx[v * KK + k];
    const int mk = maskn[v * KK + k];
    __syncthreads();   // previous compute done before overwriting xs
    // stage xs[c][tt] = masked/padded x[n][c][vk][tb-1+tt]
    for (int i = tid; i < CINC * 66; i += 256) {
      int c  = i / 66;
      int tt = i - c * 66;
      int gt = tb - 1 + tt;
      float val = 0.f;
      if (mk && gt >= 0 && gt < TLEN)
        val = x[(((size_t)n * CINC + c) * NV + vk) * TLEN + gt];
      xs[c][tt] = val;
    }
    for (int kt = 0; kt < TKK; ++kt) {
      __syncthreads();   // previous compute done before overwriting wsh
      const float4* src =
          (const float4*)(Wt + ((size_t)(v * KK + k) * TKK + kt) * (CINC * COUTC));
      for (int i = tid; i < CINC * COUTC / 4; i += 256)
        ((float4*)wsh)[i] = src[i];
      __syncthreads();   // xs + wsh ready
#pragma unroll 4
      for (int c = 0; c < CINC; ++c) {
        float xv = xs[c][t0 + kt];
        const float4* wrow = (const float4*)&wsh[c][og * 16];
#pragma unroll
        for (int j4 = 0; j4 < 4; ++j4) {
          float4 w = wrow[j4];
          acc[j4 * 4 + 0] = fmaf(w.x, xv, acc[j4 * 4 + 0]);
          acc[j4 * 4 + 1] = fmaf(w.y, xv, acc[j4 * 4 + 1]);
          acc[j4 * 4 + 2] = fmaf(w.z, xv, acc[j4 * 4 + 2]);
          acc[j4 * 4 + 3] = fmaf(w.w, xv, acc[j4 * 4 + 3]);
        }
      }
    }
  }
  // epilogue: bias + coalesced store
#pragma unroll
  for (int j = 0; j < 16; ++j) {
    int o = og * 16 + j;
    out[(((size_t)n * COUTC + o) * NV + v) * TLEN + tb + t0] =
        acc[j] + b[v * COUTC + o];
  }
}

extern "C" void kernel_launch(void* const* d_in, const int* in_sizes, int n_in,
                              void* d_out, int out_size, void* d_ws, size_t ws_size,
                              hipStream_t stream) {
  const float* x    = (const float*)d_in[0];
  const float* W    = (const float*)d_in[1];
  const float* b    = (const float*)d_in[2];
  const int*   idx  = (const int*)d_in[3];
  const int*   mask = (const int*)d_in[4];
  float* out = (float*)d_out;

  int*   maskn = (int*)d_ws;
  float* Wt    = (float*)((char*)d_ws + 512);

  hipLaunchKernelGGL(prep_mask_kernel, dim3(1), dim3(128), 0, stream, mask, maskn);
  hipLaunchKernelGGL(prep_wt_kernel, dim3(NV * KK * TKK), dim3(256), 0, stream, W, Wt);
  hipLaunchKernelGGL(lcn_main, dim3(TLEN / 64, NV, NB), dim3(256), 0, stream,
                     x, Wt, b, idx, maskn, out);
}

// Round 2
// 151.026 us; speedup vs baseline: 2.0508x; 2.0508x over previous
//
#include <hip/hip_runtime.h>
#include <hip/hip_bf16.h>

#define NB   16
#define CINC 64
#define COUTC 64
#define NV   25
#define TLEN 512
#define KK   3
#define TKK  3

typedef short short8 __attribute__((ext_vector_type(8)));
typedef float f32x4  __attribute__((ext_vector_type(4)));

// ---------------- common prep: mask normalization ----------------
__global__ void prep_mask_kernel(const int* __restrict__ mask_raw,
                                 int* __restrict__ mask_out) {
  __shared__ int fmt;
  if (threadIdx.x == 0) {
    int ok = 1;
    for (int i = 0; i < 18; ++i) {   // 72 bytes, within 75-byte buffer
      int m = mask_raw[i];
      if (m != 0 && m != 1) ok = 0;
    }
    fmt = ok;
  }
  __syncthreads();
  int i = threadIdx.x;
  if (i < NV * KK) {
    int m;
    if (fmt) m = mask_raw[i];
    else     m = (((const unsigned char*)mask_raw)[i] != 0) ? 1 : 0;
    mask_out[i] = m;
  }
}

// ================= FAST PATH (bf16 MFMA) =================
// Wt2[(v*3+k)*3+kt][s][w][lane][e] bf16, mask folded in.
//   o = 16*w + (lane&15);  c = 32*s + 8*(lane>>4) + e
__global__ void prep_wt2_kernel(const float* __restrict__ W,
                                const int* __restrict__ maskn,
                                __hip_bfloat16* __restrict__ Wt2) {
  int blk = blockIdx.x;            // v*9 + k*3 + kt
  int v = blk / 9, kkt = blk % 9, k = kkt / 3, kt = kkt % 3;
  int m = maskn[v * KK + k];
  const float* Wv = W + (size_t)v * COUTC * CINC * 9;
  __hip_bfloat16* dst = Wt2 + (size_t)blk * 4096;
  for (int i = threadIdx.x; i < 4096; i += 256) {
    int e    = i & 7;
    int lane = (i >> 3) & 63;
    int w    = (i >> 9) & 3;
    int s    = i >> 11;
    int o = 16 * w + (lane & 15);
    int c = 32 * s + 8 * (lane >> 4) + e;
    float val = m ? Wv[(o * CINC + c) * 9 + k * 3 + kt] : 0.f;
    dst[i] = __float2bfloat16(val);
  }
}

// xT[n][v][t][c] bf16  <-  x[n][c][v][t] fp32   (LDS transpose, 64c x 64t tiles)
__global__ __launch_bounds__(256) void prep_xt_kernel(
    const float* __restrict__ x, __hip_bfloat16* __restrict__ xT) {
  const int tb = blockIdx.x * 64;
  const int v  = blockIdx.y;
  const int n  = blockIdx.z;
  __shared__ float ts[64][65];
  for (int i = threadIdx.x; i < 4096; i += 256) {
    int c = i >> 6, t = i & 63;          // consecutive lanes -> consecutive t
    ts[c][t] = x[(((size_t)n * CINC + c) * NV + v) * TLEN + tb + t];
  }
  __syncthreads();
  for (int i = threadIdx.x; i < 4096; i += 256) {
    int t = i >> 6, c = i & 63;          // consecutive lanes -> consecutive c
    xT[((((size_t)n * NV + v) * TLEN) + tb + t) * CINC + c] =
        __float2bfloat16(ts[c][t]);
  }
}

// Main: one block = 64 o x 128 t for (n, v, t-chunk). 4 waves, no LDS.
__global__ __launch_bounds__(256) void lcn_mfma(
    const __hip_bfloat16* __restrict__ xT,
    const __hip_bfloat16* __restrict__ Wt2,
    const float* __restrict__ bias,
    const int* __restrict__ idx,
    float* __restrict__ out) {
  const int tb   = blockIdx.x * 128;
  const int v    = blockIdx.y;
  const int n    = blockIdx.z;
  const int tid  = threadIdx.x;
  const int lane = tid & 63;
  const int w    = tid >> 6;     // wave -> 16-o slab
  const int fr   = lane & 15;    // D col (t), A row (o)
  const int fq   = lane >> 4;    // k-chunk selector

  f32x4 acc[8];
#pragma unroll
  for (int i = 0; i < 8; ++i) acc[i] = (f32x4){0.f, 0.f, 0.f, 0.f};

  const int colbase = 8 * fq;    // c offset within a 32-wide K slice

  for (int k = 0; k < KK; ++k) {
    const int vk = idx[v * KK + k];
    const __hip_bfloat16* xv = xT + ((size_t)n * NV + vk) * TLEN * CINC;
#pragma unroll
    for (int kt = 0; kt < TKK; ++kt) {
      const __hip_bfloat16* wp = Wt2 + (size_t)((v * KK + k) * TKK + kt) * 4096;
#pragma unroll
      for (int s = 0; s < 2; ++s) {
        short8 a = *(const short8*)(wp + ((s * 4 + w) * 64 + lane) * 8);
        short8 bfrag[8];
#pragma unroll
        for (int tile = 0; tile < 8; ++tile) {
          int tg = tb + 16 * tile + fr + kt - 1;
          short8 bv = (short8){0, 0, 0, 0, 0, 0, 0, 0};
          if ((unsigned)tg < (unsigned)TLEN)
            bv = *(const short8*)(xv + (size_t)tg * CINC + 32 * s + colbase);
          bfrag[tile] = bv;
        }
#pragma unroll
        for (int tile = 0; tile < 8; ++tile)
          acc[tile] = __builtin_amdgcn_mfma_f32_16x16x32_bf16(
              a, bfrag[tile], acc[tile], 0, 0, 0);
      }
    }
  }
  // epilogue: bias + store. D: col(t)=lane&15, row(o)=4*(lane>>4)+j
#pragma unroll
  for (int tile = 0; tile < 8; ++tile) {
    int t = tb + 16 * tile + fr;
#pragma unroll
    for (int j = 0; j < 4; ++j) {
      int o = 16 * w + 4 * fq + j;
      out[(((size_t)n * COUTC + o) * NV + v) * TLEN + t] =
          acc[tile][j] + bias[v * COUTC + o];
    }
  }
}

// ================= FALLBACK PATH (round-1 fp32, known-good) =================
__global__ void prep_wt_kernel(const float* __restrict__ W,
                               float* __restrict__ Wt) {
  int v   = blockIdx.x / 9;
  int kkt = blockIdx.x % 9;
  const float* Wv = W + (size_t)v * COUTC * CINC * 9;
  float* dst = Wt + (size_t)blockIdx.x * (CINC * COUTC);
  for (int i = threadIdx.x; i < CINC * COUTC; i += 256) {
    int c = i >> 6;
    int o = i & 63;
    dst[i] = Wv[(o * CINC + c) * 9 + kkt];
  }
}

__global__ __launch_bounds__(256, 4) void lcn_main(
    const float* __restrict__ x, const float* __restrict__ Wt,
    const float* __restrict__ b, const int* __restrict__ idx,
    const int* __restrict__ maskn, float* __restrict__ out) {
  __shared__ float xs[CINC][66];
  __shared__ float wsh[CINC][COUTC];
  const int tb  = blockIdx.x * 64;
  const int v   = blockIdx.y;
  const int n   = blockIdx.z;
  const int tid = threadIdx.x;
  const int t0  = tid & 63;
  const int og  = tid >> 6;
  float acc[16];
#pragma unroll
  for (int j = 0; j < 16; ++j) acc[j] = 0.f;
  for (int k = 0; k < KK; ++k) {
    const int vk = idx[v * KK + k];
    const int mk = maskn[v * KK + k];
    __syncthreads();
    for (int i = tid; i < CINC * 66; i += 256) {
      int c  = i / 66;
      int tt = i - c * 66;
      int gt = tb - 1 + tt;
      float val = 0.f;
      if (mk && gt >= 0 && gt < TLEN)
        val = x[(((size_t)n * CINC + c) * NV + vk) * TLEN + gt];
      xs[c][tt] = val;
    }
    for (int kt = 0; kt < TKK; ++kt) {
      __syncthreads();
      const float4* src =
          (const float4*)(Wt + ((size_t)(v * KK + k) * TKK + kt) * (CINC * COUTC));
      for (int i = tid; i < CINC * COUTC / 4; i += 256)
        ((float4*)wsh)[i] = src[i];
      __syncthreads();
#pragma unroll 4
      for (int c = 0; c < CINC; ++c) {
        float xv = xs[c][t0 + kt];
        const float4* wrow = (const float4*)&wsh[c][og * 16];
#pragma unroll
        for (int j4 = 0; j4 < 4; ++j4) {
          float4 wv = wrow[j4];
          acc[j4 * 4 + 0] = fmaf(wv.x, xv, acc[j4 * 4 + 0]);
          acc[j4 * 4 + 1] = fmaf(wv.y, xv, acc[j4 * 4 + 1]);
          acc[j4 * 4 + 2] = fmaf(wv.z, xv, acc[j4 * 4 + 2]);
          acc[j4 * 4 + 3] = fmaf(wv.w, xv, acc[j4 * 4 + 3]);
        }
      }
    }
  }
#pragma unroll
  for (int j = 0; j < 16; ++j) {
    int o = og * 16 + j;
    out[(((size_t)n * COUTC + o) * NV + v) * TLEN + tb + t0] =
        acc[j] + b[v * COUTC + o];
  }
}

extern "C" void kernel_launch(void* const* d_in, const int* in_sizes, int n_in,
                              void* d_out, int out_size, void* d_ws, size_t ws_size,
                              hipStream_t stream) {
  const float* x    = (const float*)d_in[0];
  const float* W    = (const float*)d_in[1];
  const float* b    = (const float*)d_in[2];
  const int*   idx  = (const int*)d_in[3];
  const int*   mask = (const int*)d_in[4];
  float* out = (float*)d_out;

  int* maskn = (int*)d_ws;
  hipLaunchKernelGGL(prep_mask_kernel, dim3(1), dim3(128), 0, stream, mask, maskn);

  // ws layout (fast path): [0,512) maskn | [512, +1.84MB) Wt2 | then xT (26.2MB)
  const size_t WT2_BYTES = (size_t)NV * 9 * 4096 * sizeof(__hip_bfloat16);
  const size_t XT_BYTES  = (size_t)NB * NV * TLEN * CINC * sizeof(__hip_bfloat16);
  const size_t NEED      = 512 + WT2_BYTES + XT_BYTES;

  if (ws_size >= NEED) {
    __hip_bfloat16* Wt2 = (__hip_bfloat16*)((char*)d_ws + 512);
    __hip_bfloat16* xT  = (__hip_bfloat16*)((char*)d_ws + 512 + WT2_BYTES);
    hipLaunchKernelGGL(prep_wt2_kernel, dim3(NV * 9), dim3(256), 0, stream,
                       W, maskn, Wt2);
    hipLaunchKernelGGL(prep_xt_kernel, dim3(TLEN / 64, NV, NB), dim3(256), 0,
                       stream, x, xT);
    hipLaunchKernelGGL(lcn_mfma, dim3(TLEN / 128, NV, NB), dim3(256), 0, stream,
                       xT, Wt2, b, idx, out);
  } else {
    float* Wt = (float*)((char*)d_ws + 512);
    hipLaunchKernelGGL(prep_wt_kernel, dim3(NV * KK * TKK), dim3(256), 0, stream,
                       W, Wt);
    hipLaunchKernelGGL(lcn_main, dim3(TLEN / 64, NV, NB), dim3(256), 0, stream,
                       x, Wt, b, idx, maskn, out);
  }
}

// Round 3
// 61.538 us; speedup vs baseline: 5.0330x; 2.4542x over previous
//
#include <hip/hip_runtime.h>
#include <hip/hip_bf16.h>

#define NB   16
#define CINC 64
#define COUTC 64
#define NV   25
#define TLEN 512
#define KK   3
#define TKK  3

typedef short short8 __attribute__((ext_vector_type(8)));
typedef float f32x4  __attribute__((ext_vector_type(4)));
typedef float f32x16 __attribute__((ext_vector_type(16)));

#define XS_STRIDE 17408   // 17 KB per xs buffer: 130 used rows + slack (136*128)

// ---------------- mask normalization (fallback path) ----------------
__global__ void prep_mask_kernel(const int* __restrict__ mask_raw,
                                 int* __restrict__ mask_out) {
  __shared__ int fmt;
  if (threadIdx.x == 0) {
    int ok = 1;
    for (int i = 0; i < 18; ++i) {
      int m = mask_raw[i];
      if (m != 0 && m != 1) ok = 0;
    }
    fmt = ok;
  }
  __syncthreads();
  int i = threadIdx.x;
  if (i < NV * KK) {
    int m;
    if (fmt) m = mask_raw[i];
    else     m = (((const unsigned char*)mask_raw)[i] != 0) ? 1 : 0;
    mask_out[i] = m;
  }
}

// ================= FAST PATH (bf16 MFMA 32x32x16) =================
// Wt3[blk=(v*3+k)*3+kt][oslab][ks][lane][e] bf16, mask folded in.
//   o = oslab*32 + (lane&31);  c = ks*16 + 8*(lane>>5) + e
__global__ void prep_wt3_kernel(const float* __restrict__ W,
                                const unsigned char* __restrict__ mask_raw,
                                __hip_bfloat16* __restrict__ Wt3) {
  int blk = blockIdx.x;            // v*9 + k*3 + kt
  int v = blk / 9, kkt = blk % 9, k = kkt / 3, kt = kkt % 3;
  // detect bool-bytes vs int32 mask encoding
  const int* mi = (const int*)mask_raw;
  int ok = 1;
  for (int i = 0; i < 18; ++i) {
    int m = mi[i];
    if (m != 0 && m != 1) ok = 0;
  }
  int m = ok ? mi[v * KK + k] : (int)(mask_raw[v * KK + k] != 0);
  const float* Wv = W + (size_t)v * COUTC * CINC * 9;
  __hip_bfloat16* dst = Wt3 + (size_t)blk * 4096;
  for (int i = threadIdx.x; i < 4096; i += 256) {
    int e     = i & 7;
    int lane  = (i >> 3) & 63;
    int ks    = (i >> 9) & 3;
    int oslab = i >> 11;
    int o = oslab * 32 + (lane & 31);
    int c = ks * 16 + 8 * (lane >> 5) + e;
    float val = m ? Wv[(o * CINC + c) * 9 + k * 3 + kt] : 0.f;
    dst[i] = __float2bfloat16(val);
  }
}

// xT[n][v][t][c] bf16  <-  x[n][c][v][t] fp32   (LDS transpose, 64c x 64t tiles)
__global__ __launch_bounds__(256) void prep_xt_kernel(
    const float* __restrict__ x, __hip_bfloat16* __restrict__ xT) {
  const int tb = blockIdx.x * 64;
  const int v  = blockIdx.y;
  const int n  = blockIdx.z;
  __shared__ float ts[64][65];
  for (int i = threadIdx.x; i < 4096; i += 256) {
    int c = i >> 6, t = i & 63;
    ts[c][t] = x[(((size_t)n * CINC + c) * NV + v) * TLEN + tb + t];
  }
  __syncthreads();
  for (int i = threadIdx.x; i < 4096; i += 256) {
    int t = i >> 6, c = i & 63;
    xT[((((size_t)n * NV + v) * TLEN) + tb + t) * CINC + c] =
        __float2bfloat16(ts[c][t]);
  }
}

__device__ __forceinline__ const char* slab_base(const __hip_bfloat16* xT,
                                                 int n, int vk, int tb) {
  return (const char*)xT + ((ptrdiff_t)((n * NV + vk) * TLEN + tb) - 1) * 128;
}

// Stage 17 KB slab: linear LDS dest, inverse-swizzled global source (rule #21).
__device__ __forceinline__ void stage_slab(const char* gbase, char* lbase,
                                           int wave, int lane) {
  for (int c = wave; c < 17; c += 4) {
    int L = c * 1024 + lane * 16;
    int g = L ^ (((L >> 7) & 7) << 4);   // XOR only touches bits 4-6 (in-row)
    __builtin_amdgcn_global_load_lds(
        (const __attribute__((address_space(1))) void*)(gbase + g),
        (__attribute__((address_space(3))) void*)(lbase + c * 1024),
        16, 0, 0);
  }
}

// Zero halo rows at the t-boundaries (predicated; whole-row zero is
// swizzle-invariant since the XOR permutes within a 128B row).
__device__ __forceinline__ void fix_edges(char* buf, int tb, int tid) {
  if (tb == 0 && tid < 8)
    *(f32x4*)(buf + tid * 16) = (f32x4){0.f, 0.f, 0.f, 0.f};
  if (tb == TLEN - 128 && tid >= 8 && tid < 16)
    *(f32x4*)(buf + 129 * 128 + (tid - 8) * 16) = (f32x4){0.f, 0.f, 0.f, 0.f};
}

// Main: block = 64 o x 128 t for (n, v, tchunk). 4 waves:
// wave -> (oslab = w&1)*32 o, (w>>1)*64 t. W in regs, x double-buffered in LDS.
__global__ __launch_bounds__(256, 2) void lcn_mfma32(
    const __hip_bfloat16* __restrict__ xT,
    const __hip_bfloat16* __restrict__ Wt3,
    const float* __restrict__ bias,
    const int* __restrict__ idx,
    float* __restrict__ out) {
  __shared__ char xs[2][XS_STRIDE];

  const int tb    = blockIdx.x * 128;
  const int v     = blockIdx.y;
  const int n     = blockIdx.z;
  const int tid   = threadIdx.x;
  const int lane  = tid & 63;
  const int wave  = tid >> 6;
  const int oslab = wave & 1;
  const int wt    = (wave >> 1) * 64;
  const int hi    = lane >> 5;
  const int l31   = lane & 31;

  f32x16 acc0 = {};
  f32x16 acc1 = {};

  // prologue: stage k=0
  stage_slab(slab_base(xT, n, idx[v * KK + 0], tb), xs[0], wave, lane);
  __syncthreads();
  fix_edges(xs[0], tb, tid);
  __syncthreads();

  const short8* wbase = (const short8*)Wt3;

  for (int k = 0; k < KK; ++k) {
    char* cur = xs[k & 1];
    char* nxt = xs[(k & 1) ^ 1];

    // A-fragments for this k (issued first so vmcnt-wait for them
    // leaves the staging loads in flight)
    short8 a0_0, a0_1, a0_2, a0_3;
    short8 a1_0, a1_1, a1_2, a1_3;
    short8 a2_0, a2_1, a2_2, a2_3;
    {
      int blk0 = (v * KK + k) * TKK;
      const short8* p0 = wbase + (((blk0 + 0) * 2 + oslab) << 8) + lane;
      const short8* p1 = wbase + (((blk0 + 1) * 2 + oslab) << 8) + lane;
      const short8* p2 = wbase + (((blk0 + 2) * 2 + oslab) << 8) + lane;
      a0_0 = p0[0];  a0_1 = p0[64];  a0_2 = p0[128];  a0_3 = p0[192];
      a1_0 = p1[0];  a1_1 = p1[64];  a1_2 = p1[128];  a1_3 = p1[192];
      a2_0 = p2[0];  a2_1 = p2[64];  a2_2 = p2[128];  a2_3 = p2[192];
    }

    if (k < KK - 1)
      stage_slab(slab_base(xT, n, idx[v * KK + k + 1], tb), nxt, wave, lane);

#define DO_KT(KT, A0, A1, A2, A3)                                           \
  {                                                                         \
    int r0 = wt + l31 + (KT);                                               \
    int r1 = r0 + 32;                                                       \
    int base0 = r0 * 128, sw0 = (r0 & 7) << 4;                              \
    int base1 = r1 * 128, sw1 = (r1 & 7) << 4;                              \
    int co = hi * 16;                                                       \
    short8 b;                                                               \
    b = *(const short8*)(cur + base0 + ((co + 0) ^ sw0));                   \
    acc0 = __builtin_amdgcn_mfma_f32_32x32x16_bf16(A0, b, acc0, 0, 0, 0);   \
    b = *(const short8*)(cur + base1 + ((co + 0) ^ sw1));                   \
    acc1 = __builtin_amdgcn_mfma_f32_32x32x16_bf16(A0, b, acc1, 0, 0, 0);   \
    b = *(const short8*)(cur + base0 + ((co + 32) ^ sw0));                  \
    acc0 = __builtin_amdgcn_mfma_f32_32x32x16_bf16(A1, b, acc0, 0, 0, 0);   \
    b = *(const short8*)(cur + base1 + ((co + 32) ^ sw1));                  \
    acc1 = __builtin_amdgcn_mfma_f32_32x32x16_bf16(A1, b, acc1, 0, 0, 0);   \
    b = *(const short8*)(cur + base0 + ((co + 64) ^ sw0));                  \
    acc0 = __builtin_amdgcn_mfma_f32_32x32x16_bf16(A2, b, acc0, 0, 0, 0);   \
    b = *(const short8*)(cur + base1 + ((co + 64) ^ sw1));                  \
    acc1 = __builtin_amdgcn_mfma_f32_32x32x16_bf16(A2, b, acc1, 0, 0, 0);   \
    b = *(const short8*)(cur + base0 + ((co + 96) ^ sw0));                  \
    acc0 = __builtin_amdgcn_mfma_f32_32x32x16_bf16(A3, b, acc0, 0, 0, 0);   \
    b = *(const short8*)(cur + base1 + ((co + 96) ^ sw1));                  \
    acc1 = __builtin_amdgcn_mfma_f32_32x32x16_bf16(A3, b, acc1, 0, 0, 0);   \
  }

    DO_KT(0, a0_0, a0_1, a0_2, a0_3)
    DO_KT(1, a1_0, a1_1, a1_2, a1_3)
    DO_KT(2, a2_0, a2_1, a2_2, a2_3)
#undef DO_KT

    __syncthreads();           // drains vmcnt(0): staging of nxt complete
    if (k < KK - 1) {
      fix_edges(nxt, tb, tid);
      __syncthreads();
    }
  }

  // epilogue: D col(t)=lane&31, row(o)=(reg&3)+8*(reg>>2)+4*(lane>>5)
  const float* bv = bias + v * COUTC;
#pragma unroll
  for (int tile = 0; tile < 2; ++tile) {
    const f32x16& acc = tile ? acc1 : acc0;
    int t = tb + wt + 32 * tile + l31;
#pragma unroll
    for (int reg = 0; reg < 16; ++reg) {
      int o = oslab * 32 + 4 * hi + (reg & 3) + 8 * (reg >> 2);
      out[(((size_t)n * COUTC + o) * NV + v) * TLEN + t] = acc[reg] + bv[o];
    }
  }
}

// ================= FALLBACK PATH (round-1 fp32, known-good) =================
__global__ void prep_wt_kernel(const float* __restrict__ W,
                               float* __restrict__ Wt) {
  int v   = blockIdx.x / 9;
  int kkt = blockIdx.x % 9;
  const float* Wv = W + (size_t)v * COUTC * CINC * 9;
  float* dst = Wt + (size_t)blockIdx.x * (CINC * COUTC);
  for (int i = threadIdx.x; i < CINC * COUTC; i += 256) {
    int c = i >> 6;
    int o = i & 63;
    dst[i] = Wv[(o * CINC + c) * 9 + kkt];
  }
}

__global__ __launch_bounds__(256, 4) void lcn_main(
    const float* __restrict__ x, const float* __restrict__ Wt,
    const float* __restrict__ b, const int* __restrict__ idx,
    const int* __restrict__ maskn, float* __restrict__ out) {
  __shared__ float xsf[CINC][66];
  __shared__ float wsh[CINC][COUTC];
  const int tb  = blockIdx.x * 64;
  const int v   = blockIdx.y;
  const int n   = blockIdx.z;
  const int tid = threadIdx.x;
  const int t0  = tid & 63;
  const int og  = tid >> 6;
  float acc[16];
#pragma unroll
  for (int j = 0; j < 16; ++j) acc[j] = 0.f;
  for (int k = 0; k < KK; ++k) {
    const int vk = idx[v * KK + k];
    const int mk = maskn[v * KK + k];
    __syncthreads();
    for (int i = tid; i < CINC * 66; i += 256) {
      int c  = i / 66;
      int tt = i - c * 66;
      int gt = tb - 1 + tt;
      float val = 0.f;
      if (mk && gt >= 0 && gt < TLEN)
        val = x[(((size_t)n * CINC + c) * NV + vk) * TLEN + gt];
      xsf[c][tt] = val;
    }
    for (int kt = 0; kt < TKK; ++kt) {
      __syncthreads();
      const float4* src =
          (const float4*)(Wt + ((size_t)(v * KK + k) * TKK + kt) * (CINC * COUTC));
      for (int i = tid; i < CINC * COUTC / 4; i += 256)
        ((float4*)wsh)[i] = src[i];
      __syncthreads();
#pragma unroll 4
      for (int c = 0; c < CINC; ++c) {
        float xv = xsf[c][t0 + kt];
        const float4* wrow = (const float4*)&wsh[c][og * 16];
#pragma unroll
        for (int j4 = 0; j4 < 4; ++j4) {
          float4 wv = wrow[j4];
          acc[j4 * 4 + 0] = fmaf(wv.x, xv, acc[j4 * 4 + 0]);
          acc[j4 * 4 + 1] = fmaf(wv.y, xv, acc[j4 * 4 + 1]);
          acc[j4 * 4 + 2] = fmaf(wv.z, xv, acc[j4 * 4 + 2]);
          acc[j4 * 4 + 3] = fmaf(wv.w, xv, acc[j4 * 4 + 3]);
        }
      }
    }
  }
#pragma unroll
  for (int j = 0; j < 16; ++j) {
    int o = og * 16 + j;
    out[(((size_t)n * COUTC + o) * NV + v) * TLEN + tb + t0] =
        acc[j] + b[v * COUTC + o];
  }
}

extern "C" void kernel_launch(void* const* d_in, const int* in_sizes, int n_in,
                              void* d_out, int out_size, void* d_ws, size_t ws_size,
                              hipStream_t stream) {
  const float* x    = (const float*)d_in[0];
  const float* W    = (const float*)d_in[1];
  const float* b    = (const float*)d_in[2];
  const int*   idx  = (const int*)d_in[3];
  const void*  mask = (const void*)d_in[4];
  float* out = (float*)d_out;

  // ws: [0,512) maskn (fallback) | Wt3 1.84MB | xT 26.2MB | 2KB guard
  const size_t WT3_BYTES = (size_t)NV * 9 * 4096 * sizeof(__hip_bfloat16);
  const size_t XT_BYTES  = (size_t)NB * NV * TLEN * CINC * sizeof(__hip_bfloat16);
  const size_t NEED      = 512 + WT3_BYTES + XT_BYTES + 2048;

  if (ws_size >= NEED) {
    __hip_bfloat16* Wt3 = (__hip_bfloat16*)((char*)d_ws + 512);
    __hip_bfloat16* xT  = (__hip_bfloat16*)((char*)d_ws + 512 + WT3_BYTES);
    hipLaunchKernelGGL(prep_wt3_kernel, dim3(NV * 9), dim3(256), 0, stream,
                       W, (const unsigned char*)mask, Wt3);
    hipLaunchKernelGGL(prep_xt_kernel, dim3(TLEN / 64, NV, NB), dim3(256), 0,
                       stream, x, xT);
    hipLaunchKernelGGL(lcn_mfma32, dim3(TLEN / 128, NV, NB), dim3(256), 0,
                       stream, xT, Wt3, b, idx, out);
  } else {
    int*   maskn = (int*)d_ws;
    float* Wt    = (float*)((char*)d_ws + 512);
    hipLaunchKernelGGL(prep_mask_kernel, dim3(1), dim3(128), 0, stream,
                       (const int*)mask, maskn);
    hipLaunchKernelGGL(prep_wt_kernel, dim3(NV * KK * TKK), dim3(256), 0, stream,
                       W, Wt);
    hipLaunchKernelGGL(lcn_main, dim3(TLEN / 64, NV, NB), dim3(256), 0, stream,
                       x, Wt, b, idx, maskn, out);
  }
}

// Round 4
// 54.622 us; speedup vs baseline: 5.6703x; 1.1266x over previous
//
#include <hip/hip_runtime.h>
#include <hip/hip_bf16.h>

#define NB   16
#define CINC 64
#define COUTC 64
#define NV   25
#define TLEN 512
#define KK   3
#define TKK  3

typedef short short8 __attribute__((ext_vector_type(8)));
typedef float f32x4  __attribute__((ext_vector_type(4)));
typedef float f32x16 __attribute__((ext_vector_type(16)));

#define XS_STRIDE 17408   // 17 KB per xs buffer: 130 used rows + slack (136*128)
#define NWT3BLK (NV * 9)  // 225 weight-prep blocks

__device__ __forceinline__ unsigned pack_bf16(float lo, float hi) {
  __hip_bfloat16 l = __float2bfloat16(lo);
  __hip_bfloat16 h = __float2bfloat16(hi);
  unsigned short ul = *reinterpret_cast<unsigned short*>(&l);
  unsigned short uh = *reinterpret_cast<unsigned short*>(&h);
  return (unsigned)ul | ((unsigned)uh << 16);
}

// ================= fused prep: Wt3 (blocks 0..224) + xT (rest) =================
// Wt3[blk=(v*3+k)*3+kt][oslab][ks][lane][e] bf16, mask folded in.
//   o = oslab*32 + (lane&31);  c = ks*16 + 8*(lane>>5) + e
// xT[n][v][t][c] bf16 <- x[n][c][v][t] fp32 (LDS transpose, 64t x 64c tiles)
__global__ __launch_bounds__(256) void prep_all(
    const float* __restrict__ x, const float* __restrict__ W,
    const unsigned char* __restrict__ mask_raw,
    __hip_bfloat16* __restrict__ Wt3, __hip_bfloat16* __restrict__ xT) {
  __shared__ float ts[64][65];
  int bid = blockIdx.x;
  if (bid < NWT3BLK) {
    int blk = bid;                 // v*9 + k*3 + kt
    int v = blk / 9, kkt = blk % 9, k = kkt / 3, kt = kkt % 3;
    const int* mi = (const int*)mask_raw;
    int ok = 1;
    for (int i = 0; i < 18; ++i) {
      int m = mi[i];
      if (m != 0 && m != 1) ok = 0;
    }
    int m = ok ? mi[v * KK + k] : (int)(mask_raw[v * KK + k] != 0);
    const float* Wv = W + (size_t)v * COUTC * CINC * 9;
    __hip_bfloat16* dst = Wt3 + (size_t)blk * 4096;
    for (int i = threadIdx.x; i < 4096; i += 256) {
      int e     = i & 7;
      int lane  = (i >> 3) & 63;
      int ks    = (i >> 9) & 3;
      int oslab = i >> 11;
      int o = oslab * 32 + (lane & 31);
      int c = ks * 16 + 8 * (lane >> 5) + e;
      float val = m ? Wv[(o * CINC + c) * 9 + k * 3 + kt] : 0.f;
      dst[i] = __float2bfloat16(val);
    }
    return;
  }
  bid -= NWT3BLK;
  const int tb = (bid & 7) * 64;
  const int vn = bid >> 3;
  const int v  = vn % NV;
  const int n  = vn / NV;
  const int tid = threadIdx.x;
  // load: float4 over t (coalesced 1KB/instr), 4 scalar LDS writes (2-way max)
  for (int i = tid; i < 1024; i += 256) {
    int c = i >> 4, tq = (i & 15) * 4;
    float4 val = *(const float4*)(x + (((size_t)n * CINC + c) * NV + v) * TLEN + tb + tq);
    ts[c][tq + 0] = val.x;
    ts[c][tq + 1] = val.y;
    ts[c][tq + 2] = val.z;
    ts[c][tq + 3] = val.w;
  }
  __syncthreads();
  // emit: dword = bf16 pair (2c, 2c+1) at t; stores 256B contiguous per instr
  unsigned* dst = (unsigned*)(xT + (((size_t)n * NV + v) * TLEN + tb) * CINC);
  for (int i = tid; i < 2048; i += 256) {
    int c2 = i & 31, t = i >> 5;
    dst[t * 32 + c2] = pack_bf16(ts[2 * c2][t], ts[2 * c2 + 1][t]);
  }
}

__device__ __forceinline__ const char* slab_base(const __hip_bfloat16* xT,
                                                 int n, int vk, int tb) {
  return (const char*)xT + ((ptrdiff_t)((n * NV + vk) * TLEN + tb) - 1) * 128;
}

// Stage 17 KB slab: linear LDS dest, inverse-swizzled global source (rule #21).
__device__ __forceinline__ void stage_slab(const char* gbase, char* lbase,
                                           int wave, int lane) {
  for (int c = wave; c < 17; c += 4) {
    int L = c * 1024 + lane * 16;
    int g = L ^ (((L >> 7) & 7) << 4);   // XOR only touches bits 4-6 (in-row)
    __builtin_amdgcn_global_load_lds(
        (const __attribute__((address_space(1))) void*)(gbase + g),
        (__attribute__((address_space(3))) void*)(lbase + c * 1024),
        16, 0, 0);
  }
}

// Zero halo rows at the t-boundaries (whole-row zero is swizzle-invariant).
__device__ __forceinline__ void fix_edges(char* buf, int tb, int tid) {
  if (tb == 0 && tid < 8)
    *(f32x4*)(buf + tid * 16) = (f32x4){0.f, 0.f, 0.f, 0.f};
  if (tb == TLEN - 128 && tid >= 8 && tid < 16)
    *(f32x4*)(buf + 129 * 128 + (tid - 8) * 16) = (f32x4){0.f, 0.f, 0.f, 0.f};
}

// Main: block = 64 o x 128 t for (n, v, tchunk). 4 waves, each owns a 32-t
// quarter and computes BOTH 32-o slabs -> every B-frag ds_read feeds 2 MFMAs.
__global__ __launch_bounds__(256, 2) void lcn_mfma32(
    const __hip_bfloat16* __restrict__ xT,
    const __hip_bfloat16* __restrict__ Wt3,
    const float* __restrict__ bias,
    const int* __restrict__ idx,
    float* __restrict__ out) {
  __shared__ char xs[2][XS_STRIDE];

  const int tb   = blockIdx.x * 128;
  const int v    = blockIdx.y;
  const int n    = blockIdx.z;
  const int tid  = threadIdx.x;
  const int lane = tid & 63;
  const int wave = tid >> 6;
  const int wt   = wave * 32;     // this wave's 32-t quarter
  const int hi   = lane >> 5;
  const int l31  = lane & 31;

  f32x16 acc0 = {};   // o-slab 0
  f32x16 acc1 = {};   // o-slab 1

  stage_slab(slab_base(xT, n, idx[v * KK + 0], tb), xs[0], wave, lane);
  __syncthreads();
  fix_edges(xs[0], tb, tid);
  __syncthreads();

  const short8* wbase = (const short8*)Wt3;

  for (int k = 0; k < KK; ++k) {
    char* cur = xs[k & 1];
    char* nxt = xs[(k & 1) ^ 1];

    // A-fragments for this k, both o-slabs (static indexing after unroll)
    short8 a[2][3][4];
    const int blk0 = (v * KK + k) * TKK;
#pragma unroll
    for (int os = 0; os < 2; ++os)
#pragma unroll
      for (int kt = 0; kt < TKK; ++kt) {
        const short8* p = wbase + (((blk0 + kt) * 2 + os) << 8) + lane;
#pragma unroll
        for (int ks = 0; ks < 4; ++ks) a[os][kt][ks] = p[ks << 6];
      }

    if (k < KK - 1)
      stage_slab(slab_base(xT, n, idx[v * KK + k + 1], tb), nxt, wave, lane);

#pragma unroll
    for (int kt = 0; kt < TKK; ++kt) {
      const int r  = wt + l31 + kt;           // slab row (t - tb + 1)
      const char* bp = cur + r * 128;
      const int sw = (r & 7) << 4;
      const int co = hi * 16;
#pragma unroll
      for (int ks = 0; ks < 4; ++ks) {
        short8 b = *(const short8*)(bp + ((co + 32 * ks) ^ sw));
        acc0 = __builtin_amdgcn_mfma_f32_32x32x16_bf16(a[0][kt][ks], b, acc0, 0, 0, 0);
        acc1 = __builtin_amdgcn_mfma_f32_32x32x16_bf16(a[1][kt][ks], b, acc1, 0, 0, 0);
      }
    }

    __syncthreads();           // staging of nxt complete (vmcnt drained)
    if (k < KK - 1) {
      fix_edges(nxt, tb, tid);
      __syncthreads();
    }
  }

  // epilogue: D col(t)=lane&31, row(o)=(reg&3)+8*(reg>>2)+4*(lane>>5)
  const float* bv = bias + v * COUTC;
  const int t = tb + wt + l31;
#pragma unroll
  for (int os = 0; os < 2; ++os) {
    const f32x16& acc = os ? acc1 : acc0;
#pragma unroll
    for (int reg = 0; reg < 16; ++reg) {
      int o = os * 32 + 4 * hi + (reg & 3) + 8 * (reg >> 2);
      out[(((size_t)n * COUTC + o) * NV + v) * TLEN + t] = acc[reg] + bv[o];
    }
  }
}

// ================= FALLBACK PATH (round-1 fp32, known-good) =================
__global__ void prep_mask_kernel(const int* __restrict__ mask_raw,
                                 int* __restrict__ mask_out) {
  __shared__ int fmt;
  if (threadIdx.x == 0) {
    int ok = 1;
    for (int i = 0; i < 18; ++i) {
      int m = mask_raw[i];
      if (m != 0 && m != 1) ok = 0;
    }
    fmt = ok;
  }
  __syncthreads();
  int i = threadIdx.x;
  if (i < NV * KK) {
    int m;
    if (fmt) m = mask_raw[i];
    else     m = (((const unsigned char*)mask_raw)[i] != 0) ? 1 : 0;
    mask_out[i] = m;
  }
}

__global__ void prep_wt_kernel(const float* __restrict__ W,
                               float* __restrict__ Wt) {
  int v   = blockIdx.x / 9;
  int kkt = blockIdx.x % 9;
  const float* Wv = W + (size_t)v * COUTC * CINC * 9;
  float* dst = Wt + (size_t)blockIdx.x * (CINC * COUTC);
  for (int i = threadIdx.x; i < CINC * COUTC; i += 256) {
    int c = i >> 6;
    int o = i & 63;
    dst[i] = Wv[(o * CINC + c) * 9 + kkt];
  }
}

__global__ __launch_bounds__(256, 4) void lcn_main(
    const float* __restrict__ x, const float* __restrict__ Wt,
    const float* __restrict__ b, const int* __restrict__ idx,
    const int* __restrict__ maskn, float* __restrict__ out) {
  __shared__ float xsf[CINC][66];
  __shared__ float wsh[CINC][COUTC];
  const int tb  = blockIdx.x * 64;
  const int v   = blockIdx.y;
  const int n   = blockIdx.z;
  const int tid = threadIdx.x;
  const int t0  = tid & 63;
  const int og  = tid >> 6;
  float acc[16];
#pragma unroll
  for (int j = 0; j < 16; ++j) acc[j] = 0.f;
  for (int k = 0; k < KK; ++k) {
    const int vk = idx[v * KK + k];
    const int mk = maskn[v * KK + k];
    __syncthreads();
    for (int i = tid; i < CINC * 66; i += 256) {
      int c  = i / 66;
      int tt = i - c * 66;
      int gt = tb - 1 + tt;
      float val = 0.f;
      if (mk && gt >= 0 && gt < TLEN)
        val = x[(((size_t)n * CINC + c) * NV + vk) * TLEN + gt];
      xsf[c][tt] = val;
    }
    for (int kt = 0; kt < TKK; ++kt) {
      __syncthreads();
      const float4* src =
          (const float4*)(Wt + ((size_t)(v * KK + k) * TKK + kt) * (CINC * COUTC));
      for (int i = tid; i < CINC * COUTC / 4; i += 256)
        ((float4*)wsh)[i] = src[i];
      __syncthreads();
#pragma unroll 4
      for (int c = 0; c < CINC; ++c) {
        float xv = xsf[c][t0 + kt];
        const float4* wrow = (const float4*)&wsh[c][og * 16];
#pragma unroll
        for (int j4 = 0; j4 < 4; ++j4) {
          float4 wv = wrow[j4];
          acc[j4 * 4 + 0] = fmaf(wv.x, xv, acc[j4 * 4 + 0]);
          acc[j4 * 4 + 1] = fmaf(wv.y, xv, acc[j4 * 4 + 1]);
          acc[j4 * 4 + 2] = fmaf(wv.z, xv, acc[j4 * 4 + 2]);
          acc[j4 * 4 + 3] = fmaf(wv.w, xv, acc[j4 * 4 + 3]);
        }
      }
    }
  }
#pragma unroll
  for (int j = 0; j < 16; ++j) {
    int o = og * 16 + j;
    out[(((size_t)n * COUTC + o) * NV + v) * TLEN + tb + t0] =
        acc[j] + b[v * COUTC + o];
  }
}

extern "C" void kernel_launch(void* const* d_in, const int* in_sizes, int n_in,
                              void* d_out, int out_size, void* d_ws, size_t ws_size,
                              hipStream_t stream) {
  const float* x    = (const float*)d_in[0];
  const float* W    = (const float*)d_in[1];
  const float* b    = (const float*)d_in[2];
  const int*   idx  = (const int*)d_in[3];
  const void*  mask = (const void*)d_in[4];
  float* out = (float*)d_out;

  // ws: [0,512) maskn (fallback) | Wt3 1.84MB | xT 26.2MB | 2KB guard
  const size_t WT3_BYTES = (size_t)NV * 9 * 4096 * sizeof(__hip_bfloat16);
  const size_t XT_BYTES  = (size_t)NB * NV * TLEN * CINC * sizeof(__hip_bfloat16);
  const size_t NEED      = 512 + WT3_BYTES + XT_BYTES + 2048;

  if (ws_size >= NEED) {
    __hip_bfloat16* Wt3 = (__hip_bfloat16*)((char*)d_ws + 512);
    __hip_bfloat16* xT  = (__hip_bfloat16*)((char*)d_ws + 512 + WT3_BYTES);
    hipLaunchKernelGGL(prep_all, dim3(NWT3BLK + 8 * NV * NB), dim3(256), 0,
                       stream, x, W, (const unsigned char*)mask, Wt3, xT);
    hipLaunchKernelGGL(lcn_mfma32, dim3(TLEN / 128, NV, NB), dim3(256), 0,
                       stream, xT, Wt3, b, idx, out);
  } else {
    int*   maskn = (int*)d_ws;
    float* Wt    = (float*)((char*)d_ws + 512);
    hipLaunchKernelGGL(prep_mask_kernel, dim3(1), dim3(128), 0, stream,
                       (const int*)mask, maskn);
    hipLaunchKernelGGL(prep_wt_kernel, dim3(NV * KK * TKK), dim3(256), 0, stream,
                       W, Wt);
    hipLaunchKernelGGL(lcn_main, dim3(TLEN / 64, NV, NB), dim3(256), 0, stream,
                       x, Wt, b, idx, maskn, out);
  }
}

// Round 5
// 52.885 us; speedup vs baseline: 5.8565x; 1.0328x over previous
//
#include <hip/hip_runtime.h>
#include <hip/hip_bf16.h>

#define NB   16
#define CINC 64
#define COUTC 64
#define NV   25
#define TLEN 512
#define KK   3
#define TKK  3

typedef short short8 __attribute__((ext_vector_type(8)));
typedef float f32x4  __attribute__((ext_vector_type(4)));
typedef float f32x16 __attribute__((ext_vector_type(16)));

#define XT_ROWS 514        // padded: row 0 = t=-1 (zero), rows 1..512 = t, row 513 = t=512 (zero)
#define XS_BYTES 16640     // 130 rows * 128 B per slab buffer
#define NWT3BLK (NV * 9)   // 225 weight-prep blocks

__device__ __forceinline__ unsigned pack_bf16(float lo, float hi) {
  __hip_bfloat16 l = __float2bfloat16(lo);
  __hip_bfloat16 h = __float2bfloat16(hi);
  unsigned short ul = *reinterpret_cast<unsigned short*>(&l);
  unsigned short uh = *reinterpret_cast<unsigned short*>(&h);
  return (unsigned)ul | ((unsigned)uh << 16);
}

// ================= fused prep: Wt3 (blocks 0..224) + padded xT (rest) ========
// Wt3[blk=(v*3+k)*3+kt][oslab][ks][lane][e] bf16, mask folded in.
//   o = oslab*32 + (lane&31);  c = ks*16 + 8*(lane>>5) + e
// xT[n][v][rp][c] bf16, rp = t+1, rows 0 and 513 zeroed.
__global__ __launch_bounds__(256) void prep_all(
    const float* __restrict__ x, const float* __restrict__ W,
    const unsigned char* __restrict__ mask_raw,
    __hip_bfloat16* __restrict__ Wt3, __hip_bfloat16* __restrict__ xT) {
  __shared__ float ts[64][65];
  int bid = blockIdx.x;
  if (bid < NWT3BLK) {
    int blk = bid;                 // v*9 + k*3 + kt
    int v = blk / 9, kkt = blk % 9, k = kkt / 3, kt = kkt % 3;
    const int* mi = (const int*)mask_raw;
    int ok = 1;
    for (int i = 0; i < 18; ++i) {
      int m = mi[i];
      if (m != 0 && m != 1) ok = 0;
    }
    int m = ok ? mi[v * KK + k] : (int)(mask_raw[v * KK + k] != 0);
    const float* Wv = W + (size_t)v * COUTC * CINC * 9;
    __hip_bfloat16* dst = Wt3 + (size_t)blk * 4096;
    for (int i = threadIdx.x; i < 4096; i += 256) {
      int e     = i & 7;
      int lane  = (i >> 3) & 63;
      int ks    = (i >> 9) & 3;
      int oslab = i >> 11;
      int o = oslab * 32 + (lane & 31);
      int c = ks * 16 + 8 * (lane >> 5) + e;
      float val = m ? Wv[(o * CINC + c) * 9 + k * 3 + kt] : 0.f;
      dst[i] = __float2bfloat16(val);
    }
    return;
  }
  bid -= NWT3BLK;
  const int tb = (bid & 7) * 64;
  const int vn = bid >> 3;
  const int v  = vn % NV;
  const int n  = vn / NV;
  const int tid = threadIdx.x;
  // load: float4 over t (coalesced), transpose via LDS (stride 65: <=2-way)
  for (int i = tid; i < 1024; i += 256) {
    int c = i >> 4, tq = (i & 15) * 4;
    float4 val = *(const float4*)(x + (((size_t)n * CINC + c) * NV + v) * TLEN + tb + tq);
    ts[c][tq + 0] = val.x;
    ts[c][tq + 1] = val.y;
    ts[c][tq + 2] = val.z;
    ts[c][tq + 3] = val.w;
  }
  __syncthreads();
  // emit packed bf16 pairs; 256 B contiguous per wave-instr
  unsigned* base = (unsigned*)(xT + ((size_t)(n * NV + v) * XT_ROWS) * CINC);
  for (int i = tid; i < 2048; i += 256) {
    int c2 = i & 31, t = i >> 5;
    base[(tb + 1 + t) * 32 + c2] = pack_bf16(ts[2 * c2][t], ts[2 * c2 + 1][t]);
  }
  // zero halo rows
  if (tb == 0 && tid < 32) base[tid] = 0u;
  if (tb == TLEN - 64 && tid < 32) base[513 * 32 + tid] = 0u;
}

__device__ __forceinline__ const char* slab_base(const __hip_bfloat16* xT,
                                                 int n, int vk, int tb) {
  return (const char*)xT + ((size_t)(n * NV + vk) * XT_ROWS + tb) * 128;
}

// Stage 16.6 KB slab: linear LDS dest, involution-swizzled global source.
__device__ __forceinline__ void stage_slab(const char* gbase, char* lbase,
                                           int wave, int lane) {
  for (int c = wave; c < 17; c += 4) {
    int L = c * 1024 + lane * 16;
    if (L < XS_BYTES) {
      int g = L ^ (((L >> 7) & 7) << 4);   // XOR bits 4-6 by row bits 7-9
      __builtin_amdgcn_global_load_lds(
          (const __attribute__((address_space(1))) void*)(gbase + g),
          (__attribute__((address_space(3))) void*)(lbase + c * 1024),
          16, 0, 0);
    }
  }
}

// Main: block = 64 o x 128 t x 2 n for (v, tchunk, npair). 4 waves; wave owns
// a 32-t quarter, computes both o-slabs for both n. k-outer: A-frags in regs
// per k, reused across the n-pair -> W L2 traffic halved vs per-n blocks.
__global__ __launch_bounds__(256, 2) void lcn_mfma32(
    const __hip_bfloat16* __restrict__ xT,
    const __hip_bfloat16* __restrict__ Wt3,
    const float* __restrict__ bias,
    const int* __restrict__ idx,
    float* __restrict__ out) {
  __shared__ char xs[2][2][XS_BYTES];   // [phase][n-of-pair]

  const int tb   = blockIdx.x * 128;
  const int np   = blockIdx.y;
  const int v    = blockIdx.z;
  const int n0   = np * 2;
  const int tid  = threadIdx.x;
  const int lane = tid & 63;
  const int wave = tid >> 6;
  const int wt   = wave * 32;
  const int hi   = lane >> 5;
  const int l31  = lane & 31;

  f32x16 acc00 = {}, acc01 = {};   // n0: oslab0, oslab1
  f32x16 acc10 = {}, acc11 = {};   // n1

  // prologue: stage k=0 slabs for both n
  {
    const int vk0 = idx[v * KK + 0];
    stage_slab(slab_base(xT, n0, vk0, tb),     xs[0][0], wave, lane);
    stage_slab(slab_base(xT, n0 + 1, vk0, tb), xs[0][1], wave, lane);
  }

  const short8* wbase = (const short8*)Wt3;

#define COMPUTE_SLAB(BUF, ACC0, ACC1)                                          \
  _Pragma("unroll")                                                            \
  for (int kt = 0; kt < TKK; ++kt) {                                           \
    const int r = wt + l31 + kt;                                               \
    const char* bp = (BUF) + r * 128;                                          \
    const int sw = (r & 7) << 4;                                               \
    const int co = hi * 16;                                                    \
    _Pragma("unroll")                                                          \
    for (int ks = 0; ks < 4; ++ks) {                                           \
      short8 bfr = *(const short8*)(bp + ((co + 32 * ks) ^ sw));               \
      ACC0 = __builtin_amdgcn_mfma_f32_32x32x16_bf16(a[0][kt][ks], bfr, ACC0,  \
                                                     0, 0, 0);                 \
      ACC1 = __builtin_amdgcn_mfma_f32_32x32x16_bf16(a[1][kt][ks], bfr, ACC1,  \
                                                     0, 0, 0);                 \
    }                                                                          \
  }

  for (int k = 0; k < KK; ++k) {
    // A-frags for this k (both o-slabs); issued before the barrier so L2
    // latency overlaps the barrier wait.
    short8 a[2][TKK][4];
    const int blk0 = (v * KK + k) * TKK;
#pragma unroll
    for (int os = 0; os < 2; ++os)
#pragma unroll
      for (int kt = 0; kt < TKK; ++kt) {
        const short8* p = wbase + (((blk0 + kt) * 2 + os) << 8) + lane;
#pragma unroll
        for (int ks = 0; ks < 4; ++ks) a[os][kt][ks] = p[ks << 6];
      }

    __syncthreads();   // phase-k slabs staged; previous phase fully consumed

    if (k < KK - 1) {
      const int vk1 = idx[v * KK + k + 1];
      char* nbuf0 = xs[(k + 1) & 1][0];
      char* nbuf1 = xs[(k + 1) & 1][1];
      stage_slab(slab_base(xT, n0, vk1, tb),     nbuf0, wave, lane);
      stage_slab(slab_base(xT, n0 + 1, vk1, tb), nbuf1, wave, lane);
    }

    const char* cb0 = xs[k & 1][0];
    const char* cb1 = xs[k & 1][1];
    COMPUTE_SLAB(cb0, acc00, acc01)
    COMPUTE_SLAB(cb1, acc10, acc11)
  }
#undef COMPUTE_SLAB

  // epilogue: D col(t)=lane&31, row(o)=(reg&3)+8*(reg>>2)+4*(lane>>5)
  const float* bv = bias + v * COUTC;
  const int t = tb + wt + l31;
#pragma unroll
  for (int nn = 0; nn < 2; ++nn) {
#pragma unroll
    for (int os = 0; os < 2; ++os) {
      const f32x16& acc = nn ? (os ? acc11 : acc10) : (os ? acc01 : acc00);
#pragma unroll
      for (int reg = 0; reg < 16; ++reg) {
        int o = os * 32 + 4 * hi + (reg & 3) + 8 * (reg >> 2);
        out[(((size_t)(n0 + nn) * COUTC + o) * NV + v) * TLEN + t] =
            acc[reg] + bv[o];
      }
    }
  }
}

// ================= FALLBACK PATH (round-1 fp32, known-good) =================
__global__ void prep_mask_kernel(const int* __restrict__ mask_raw,
                                 int* __restrict__ mask_out) {
  __shared__ int fmt;
  if (threadIdx.x == 0) {
    int ok = 1;
    for (int i = 0; i < 18; ++i) {
      int m = mask_raw[i];
      if (m != 0 && m != 1) ok = 0;
    }
    fmt = ok;
  }
  __syncthreads();
  int i = threadIdx.x;
  if (i < NV * KK) {
    int m;
    if (fmt) m = mask_raw[i];
    else     m = (((const unsigned char*)mask_raw)[i] != 0) ? 1 : 0;
    mask_out[i] = m;
  }
}

__global__ void prep_wt_kernel(const float* __restrict__ W,
                               float* __restrict__ Wt) {
  int v   = blockIdx.x / 9;
  int kkt = blockIdx.x % 9;
  const float* Wv = W + (size_t)v * COUTC * CINC * 9;
  float* dst = Wt + (size_t)blockIdx.x * (CINC * COUTC);
  for (int i = threadIdx.x; i < CINC * COUTC; i += 256) {
    int c = i >> 6;
    int o = i & 63;
    dst[i] = Wv[(o * CINC + c) * 9 + kkt];
  }
}

__global__ __launch_bounds__(256, 4) void lcn_main(
    const float* __restrict__ x, const float* __restrict__ Wt,
    const float* __restrict__ b, const int* __restrict__ idx,
    const int* __restrict__ maskn, float* __restrict__ out) {
  __shared__ float xsf[CINC][66];
  __shared__ float wsh[CINC][COUTC];
  const int tb  = blockIdx.x * 64;
  const int v   = blockIdx.y;
  const int n   = blockIdx.z;
  const int tid = threadIdx.x;
  const int t0  = tid & 63;
  const int og  = tid >> 6;
  float acc[16];
#pragma unroll
  for (int j = 0; j < 16; ++j) acc[j] = 0.f;
  for (int k = 0; k < KK; ++k) {
    const int vk = idx[v * KK + k];
    const int mk = maskn[v * KK + k];
    __syncthreads();
    for (int i = tid; i < CINC * 66; i += 256) {
      int c  = i / 66;
      int tt = i - c * 66;
      int gt = tb - 1 + tt;
      float val = 0.f;
      if (mk && gt >= 0 && gt < TLEN)
        val = x[(((size_t)n * CINC + c) * NV + vk) * TLEN + gt];
      xsf[c][tt] = val;
    }
    for (int kt = 0; kt < TKK; ++kt) {
      __syncthreads();
      const float4* src =
          (const float4*)(Wt + ((size_t)(v * KK + k) * TKK + kt) * (CINC * COUTC));
      for (int i = tid; i < CINC * COUTC / 4; i += 256)
        ((float4*)wsh)[i] = src[i];
      __syncthreads();
#pragma unroll 4
      for (int c = 0; c < CINC; ++c) {
        float xv = xsf[c][t0 + kt];
        const float4* wrow = (const float4*)&wsh[c][og * 16];
#pragma unroll
        for (int j4 = 0; j4 < 4; ++j4) {
          float4 wv = wrow[j4];
          acc[j4 * 4 + 0] = fmaf(wv.x, xv, acc[j4 * 4 + 0]);
          acc[j4 * 4 + 1] = fmaf(wv.y, xv, acc[j4 * 4 + 1]);
          acc[j4 * 4 + 2] = fmaf(wv.z, xv, acc[j4 * 4 + 2]);
          acc[j4 * 4 + 3] = fmaf(wv.w, xv, acc[j4 * 4 + 3]);
        }
      }
    }
  }
#pragma unroll
  for (int j = 0; j < 16; ++j) {
    int o = og * 16 + j;
    out[(((size_t)n * COUTC + o) * NV + v) * TLEN + tb + t0] =
        acc[j] + b[v * COUTC + o];
  }
}

extern "C" void kernel_launch(void* const* d_in, const int* in_sizes, int n_in,
                              void* d_out, int out_size, void* d_ws, size_t ws_size,
                              hipStream_t stream) {
  const float* x    = (const float*)d_in[0];
  const float* W    = (const float*)d_in[1];
  const float* b    = (const float*)d_in[2];
  const int*   idx  = (const int*)d_in[3];
  const void*  mask = (const void*)d_in[4];
  float* out = (float*)d_out;

  // ws: [0,512) maskn (fallback) | Wt3 1.84MB | xT padded 26.3MB | guard
  const size_t WT3_BYTES = (size_t)NV * 9 * 4096 * sizeof(__hip_bfloat16);
  const size_t XT_BYTES  = (size_t)NB * NV * XT_ROWS * CINC * sizeof(__hip_bfloat16);
  const size_t NEED      = 512 + WT3_BYTES + XT_BYTES + 2048;

  if (ws_size >= NEED) {
    __hip_bfloat16* Wt3 = (__hip_bfloat16*)((char*)d_ws + 512);
    __hip_bfloat16* xT  = (__hip_bfloat16*)((char*)d_ws + 512 + WT3_BYTES);
    hipLaunchKernelGGL(prep_all, dim3(NWT3BLK + 8 * NV * NB), dim3(256), 0,
                       stream, x, W, (const unsigned char*)mask, Wt3, xT);
    hipLaunchKernelGGL(lcn_mfma32, dim3(TLEN / 128, NB / 2, NV), dim3(256), 0,
                       stream, xT, Wt3, b, idx, out);
  } else {
    int*   maskn = (int*)d_ws;
    float* Wt    = (float*)((char*)d_ws + 512);
    hipLaunchKernelGGL(prep_mask_kernel, dim3(1), dim3(128), 0, stream,
                       (const int*)mask, maskn);
    hipLaunchKernelGGL(prep_wt_kernel, dim3(NV * KK * TKK), dim3(256), 0, stream,
                       W, Wt);
    hipLaunchKernelGGL(lcn_main, dim3(TLEN / 64, NV, NB), dim3(256), 0, stream,
                       x, Wt, b, idx, maskn, out);
  }
}